// Round 1
// baseline (9.392 us; speedup 1.0000x reference)
//
#include <hip/hip_runtime.h>

// GlimpseSensor: rho[b,p,i,j,c] = images[b, fy - 8*2^p + i*2^p, fx - 8*2^p + j*2^p, c]
// (zero outside the image), fixations[b] = (fy, fx) stored as float32 at the tail.
// The legacy TF bilinear resize with integer scale factor is exact strided
// subsampling (frac coords are all zero), so no interpolation is needed.

#define BB 64
#define HH 512
#define WW 512
#define CC 3
#define GW 16
#define KK 3

__global__ void GlimpseSensor_45767171506547_kernel(const float* __restrict__ images,
                                                    const float* __restrict__ loc,
                                                    float* __restrict__ out) {
    const int rho_n = BB * KK * GW * GW * CC;  // 147456
    int idx = blockIdx.x * blockDim.x + threadIdx.x;
    if (idx < rho_n) {
        int c = idx % CC;
        int t = idx / CC;
        int j = t % GW; t /= GW;
        int i = t % GW; t /= GW;
        int p = t % KK;
        int b = t / KK;

        float l0 = loc[b * 2 + 0];
        float l1 = loc[b * 2 + 1];
        // jnp.round rounds half-to-even; rintf does too (default rounding mode).
        int fy = (int)rintf((l0 + 1.0f) * 0.5f * (float)(HH - 1));
        int fx = (int)rintf((l1 + 1.0f) * 0.5f * (float)(WW - 1));

        int half = (GW / 2) << p;  // 8, 16, 32
        int step = 1 << p;         // 1, 2, 4
        int y = fy - half + i * step;
        int x = fx - half + j * step;

        float v = 0.0f;
        if ((unsigned)y < (unsigned)HH && (unsigned)x < (unsigned)WW)
            v = images[((size_t)(b * HH + y) * WW + x) * CC + c];
        out[idx] = v;
    } else if (idx < rho_n + BB * 2) {
        int t = idx - rho_n;
        int b = t >> 1;
        int comp = t & 1;
        float l = loc[b * 2 + comp];
        int f = (int)rintf((l + 1.0f) * 0.5f * (float)(HH - 1));  // H == W
        out[idx] = (float)f;
    }
}

extern "C" void kernel_launch(void* const* d_in, const int* in_sizes, int n_in,
                              void* d_out, int out_size, void* d_ws, size_t ws_size,
                              hipStream_t stream) {
    const float* images = (const float*)d_in[0];
    const float* loc = (const float*)d_in[1];
    float* out = (float*)d_out;

    const int total = BB * KK * GW * GW * CC + BB * 2;  // 147584
    const int block = 256;
    const int grid = (total + block - 1) / block;       // 577
    GlimpseSensor_45767171506547_kernel<<<grid, block, 0, stream>>>(images, loc, out);
}